// Round 12
// baseline (79.436 us; speedup 1.0000x reference)
//
#include <hip/hip_runtime.h>

typedef _Float16 h2 __attribute__((ext_vector_type(2)));
typedef _Float16 h8 __attribute__((ext_vector_type(8)));
typedef float f4 __attribute__((ext_vector_type(4)));
typedef unsigned int uint32;

#define NVAL 20
#define CDIM 64
#define HW   65536
#define NPIX (4*HW)

#define BLK   512
#define NWAVE (BLK/64)
#define MAXTILES 28               // sum ceil(n_k/64) <= 8 + 19 = 27
#define MAXSLOT  (MAXTILES*64)

// ---- packed f16 tables in ws (bytes) ----
#define KN_OFF      0
#define KN_KSTRIDE  2560          // per class: 20 j-rows x 128 B (c-contig, normalized)
#define VAL_OFF     (20*KN_KSTRIDE)      // 51200
#define VAL_KSTRIDE 4096          // per class: 64 c-rows x 64 B (32 j-slots)
#define VAL_CSTRIDE 64

// ---- LDS layout (bytes) ----
#define ROW_STRIDE 144            // 64 f16 (128 B) + 16 pad; rows hold W then O
#define ROWS_BYTES (BLK*ROW_STRIDE)          // 73728
#define PERM_OFF  ROWS_BYTES                 // MAXSLOT u16 (3584)
#define TCLS_OFF  (PERM_OFF + MAXSLOT*2)     // MAXTILES int (112)
#define FLAG_OFF  (TCLS_OFF + MAXTILES*4)    // MAXTILES int (112)
#define CNT_OFF   (FLAG_OFF + MAXTILES*4)    // 24 int
#define LDS_TOTAL (CNT_OFF + 24*4 + 16)      // ~77.7 KB -> 2 blocks/CU

static __device__ __forceinline__ h2 bch2(uint32 u) { return __builtin_bit_cast(h2, u); }
static __device__ __forceinline__ uint32 bcu(h2 v) { return __builtin_bit_cast(uint32, v); }
static __device__ __forceinline__ h8 bch8(uint4 u) { return __builtin_bit_cast(h8, u); }
static __device__ __forceinline__ h2 pkrtz(float a, float b) {
    return __builtin_bit_cast(h2, __builtin_amdgcn_cvt_pkrtz(a, b));
}

// ---------------------------------------------------------------------------
// Prep: build packed f16 tables in ws (unchanged, verified since round 5).
// ---------------------------------------------------------------------------
__global__ void prep_kernel(const float* __restrict__ key,
                            const float* __restrict__ val,
                            unsigned char* __restrict__ ws) {
    int i = blockIdx.x * 256 + threadIdx.x;
    if (i < 20*CDIM) {
        int k = i >> 6, c = i & 63;
        const float* vb = val + k*NVAL*CDIM + c;     // val[k][j][c]
        float v[NVAL];
        float s = 0.f;
        #pragma unroll
        for (int j = 0; j < NVAL; j++) { v[j] = vb[j*CDIM]; s += v[j]; }
        float t = 0.f;
        for (int kk = 0; kk < 20; kk++) {
            const float* vb2 = val + kk*NVAL*CDIM + c;
            #pragma unroll
            for (int j = 0; j < NVAL; j++) t += vb2[j*CDIM];
        }
        float rest = (t - s) * (1.0f/NVAL);
        uint32* row = (uint32*)(ws + VAL_OFF + (size_t)k*VAL_KSTRIDE + c*VAL_CSTRIDE);
        #pragma unroll
        for (int jp = 0; jp < 10; jp++) row[jp] = bcu(pkrtz(v[2*jp], v[2*jp+1]));
        row[10] = bcu(pkrtz(rest, 0.f));
        #pragma unroll
        for (int jp = 11; jp < 16; jp++) row[jp] = 0u;
    } else if (i < 20*CDIM + 20*NVAL) {
        int idx = i - 20*CDIM;
        int k = idx / NVAL, j = idx % NVAL;
        const float* kb = key + k*CDIM*NVAL + j;     // key[k][c][j]
        float x[CDIM];
        float ssq = 0.f;
        #pragma unroll
        for (int c = 0; c < CDIM; c++) { x[c] = kb[c*NVAL]; ssq = fmaf(x[c], x[c], ssq); }
        float inv = 1.0f / fmaxf(sqrtf(ssq), 1e-12f);
        uint32* row = (uint32*)(ws + KN_OFF + (size_t)k*KN_KSTRIDE + j*128);
        #pragma unroll
        for (int cp = 0; cp < 32; cp++) row[cp] = bcu(pkrtz(x[2*cp]*inv, x[2*cp+1]*inv));
    }
}

// every thread redundantly scans the 20 counters: {my_base_slot, n_tiles}
static __device__ __forceinline__ int2 scan20(const int* cnt, int cls) {
    int acc = 0, mb = 0;
    #pragma unroll
    for (int k = 1; k <= 20; k++) {
        if (k == cls) mb = acc;
        acc += (cnt[k] + 63) & ~63;
    }
    return make_int2(mb, acc >> 6);
}

// ---------------------------------------------------------------------------
// Main: 512 blocks x 512 threads (2 blocks/CU). Class-pure 64-px wave-tiles.
// NO stage phase: X is demand-gathered from global content inside the tile
// loop as MFMA b-fragments (16 planar dwords per lane per subtile; the 4
// g-lanes of a pixel shfl-reduce its ssq). HBM reads thus interleave with
// MFMA/softmax -> no stage/middle phase-lock. W/O round-trip via LDS rows,
// per-tile flags + self-service coalesced store (r10-proven).
// ---------------------------------------------------------------------------
__global__ __launch_bounds__(BLK, 4) void main_kernel(
        const float* __restrict__ content, const int* __restrict__ seg,
        const unsigned char* __restrict__ tabs, float* __restrict__ out) {
    extern __shared__ unsigned char lds[];
    unsigned short* perm = (unsigned short*)(lds + PERM_OFF);
    int* tcls  = (int*)(lds + TCLS_OFF);
    int* flags = (int*)(lds + FLAG_OFF);
    int* cnt   = (int*)(lds + CNT_OFF);

    const int tid  = threadIdx.x;
    const int bid  = (int)((blockIdx.x & 7) * 64 + (blockIdx.x >> 3));  // XCD swizzle
    const int gp0  = bid * BLK;
    const int b    = gp0 >> 16;
    const int pim0 = gp0 & (HW - 1);
    const float* cbase = content + (size_t)b * CDIM * HW + pim0;
    float* obase = out + (size_t)b * CDIM * HW + pim0;

    if (tid < 24) cnt[tid] = 0;
    if (tid < MAXTILES) flags[tid] = 0;
    for (int i = tid; i < MAXSLOT; i += BLK) perm[i] = 0xFFFFu;
    __syncthreads();

    const int cls = seg[gp0 + tid] + 1;          // 1..19
    const int myrank = atomicAdd(&cnt[cls], 1);
    __syncthreads();                              // histogram complete

    const int2 s = scan20(cnt, cls);              // (my base slot, n tiles)
    const int myslot = s.x + myrank;
    const int mytile = myslot >> 6;
    {
        perm[myslot] = (unsigned short)tid;       // local pixel index
        tcls[mytile] = cls;                       // class-pure tile
    }
    __syncthreads();                              // perm/tcls complete

    const int nt   = s.y;
    const int wave = tid >> 6, lane = tid & 63;
    const int g = lane >> 4, r16 = lane & 15;

    for (int t = wave; t < nt; t += NWAVE) {
        const int u = __builtin_amdgcn_readfirstlane(tcls[t]);

        int px[4], rowb[4];
        bool mine[4];
        #pragma unroll
        for (int n = 0; n < 4; n++) {
            int v = perm[t*64 + n*16 + r16];      // same slot for all 4 g-lanes
            mine[n] = (v != 0xFFFF);
            px[n]  = mine[n] ? v : 0;
            rowb[n] = px[n] * ROW_STRIDE;
        }

        // ---- demand-gather X fragments + distributed ssq ----
        // lane (g,r16) of subtile n: channels {g*8..+7} and {32+g*8..+7} of
        // pixel px[n]; 4 g-lanes cover all 64 channels -> shfl_xor reduce.
        uint4 bsc[4][2];
        float invn[4];
        #pragma unroll
        for (int n = 0; n < 4; n++) {
            const float* cp = cbase + px[n];
            float ssq = 0.f;
            #pragma unroll
            for (int ks = 0; ks < 2; ks++) {
                float x0 = cp[(size_t)(ks*32 + g*8 + 0) * HW];
                float x1 = cp[(size_t)(ks*32 + g*8 + 1) * HW];
                float x2 = cp[(size_t)(ks*32 + g*8 + 2) * HW];
                float x3 = cp[(size_t)(ks*32 + g*8 + 3) * HW];
                float x4 = cp[(size_t)(ks*32 + g*8 + 4) * HW];
                float x5 = cp[(size_t)(ks*32 + g*8 + 5) * HW];
                float x6 = cp[(size_t)(ks*32 + g*8 + 6) * HW];
                float x7 = cp[(size_t)(ks*32 + g*8 + 7) * HW];
                ssq = fmaf(x0,x0,ssq); ssq = fmaf(x1,x1,ssq);
                ssq = fmaf(x2,x2,ssq); ssq = fmaf(x3,x3,ssq);
                ssq = fmaf(x4,x4,ssq); ssq = fmaf(x5,x5,ssq);
                ssq = fmaf(x6,x6,ssq); ssq = fmaf(x7,x7,ssq);
                uint4 f;
                f.x = bcu(pkrtz(x0, x1)); f.y = bcu(pkrtz(x2, x3));
                f.z = bcu(pkrtz(x4, x5)); f.w = bcu(pkrtz(x6, x7));
                bsc[n][ks] = f;
            }
            ssq += __shfl_xor(ssq, 16, 64);
            ssq += __shfl_xor(ssq, 32, 64);
            invn[n] = 1.0f / fmaxf(sqrtf(ssq), 1e-12f);
        }

        // ---- scores S^T[j][p] = sum_c Kn^T[j][c] * X^T[c][p] ----
        const unsigned char* knc = tabs + KN_OFF + (size_t)u * KN_KSTRIDE;
        uint4 a_sc[2][2];
        #pragma unroll
        for (int m = 0; m < 2; m++)
            #pragma unroll
            for (int ks = 0; ks < 2; ks++)
                a_sc[m][ks] = *(const uint4*)(knc + (m*16 + r16)*128 + (ks*32 + g*8)*2);

        f4 sacc[2][4];
        #pragma unroll
        for (int m = 0; m < 2; m++)
            #pragma unroll
            for (int n = 0; n < 4; n++) sacc[m][n] = (f4){0.f,0.f,0.f,0.f};
        #pragma unroll
        for (int ks = 0; ks < 2; ks++)
            #pragma unroll
            for (int m = 0; m < 2; m++)
                #pragma unroll
                for (int n = 0; n < 4; n++)
                    sacc[m][n] = __builtin_amdgcn_mfma_f32_16x16x32_f16(
                        bch8(a_sc[m][ks]), bch8(bsc[n][ks]), sacc[m][n], 0, 0, 0);

        // ---- softmax; lane holds j = m*16 + g*4 + r for pixel p = n*16+r16 ----
        uint2 w0[4], w1[4];
        #pragma unroll
        for (int n = 0; n < 4; n++) {
            float e0[4], e1[4];
            #pragma unroll
            for (int r = 0; r < 4; r++) e0[r] = __expf(sacc[0][n][r] * invn[n]);
            float arg1 = (g == 0) ? invn[n] : 0.0f;     // j>=20 masked
            #pragma unroll
            for (int r = 0; r < 4; r++) e1[r] = __expf(sacc[1][n][r] * arg1);
            float sum = e0[0]+e0[1]+e0[2]+e0[3];
            sum += (g == 0) ? (e1[0]+e1[1]+e1[2]+e1[3]) : 0.0f;
            sum += __shfl_xor(sum, 16, 64);
            sum += __shfl_xor(sum, 32, 64);
            float wsc = 1.0f / sum;
            w0[n].x = bcu(pkrtz(e0[0]*wsc, e0[1]*wsc));
            w0[n].y = bcu(pkrtz(e0[2]*wsc, e0[3]*wsc));
            uint2 t1;
            if (g == 0)      { t1.x = bcu(pkrtz(e1[0]*wsc, e1[1]*wsc));
                               t1.y = bcu(pkrtz(e1[2]*wsc, e1[3]*wsc)); }
            else if (g == 1) { t1.x = 0x00003C00u; t1.y = 0u; }  // j20=1.0 (rest)
            else             { t1.x = 0u; t1.y = 0u; }
            w1[n] = t1;
        }
        // write W into pixel's LDS row: j-contiguous 32 f16 at offset 0
        #pragma unroll
        for (int n = 0; n < 4; n++) {
            if (mine[n]) {
                *(uint2*)(lds + rowb[n] + g*8)      = w0[n];
                *(uint2*)(lds + rowb[n] + 32 + g*8) = w1[n];
            }
        }

        // ---- PV O^T[c][p] = sum_j V^T[c][j] * W^T[j][p] (K=32) ----
        uint4 b_pv[4];
        #pragma unroll
        for (int n = 0; n < 4; n++)
            b_pv[n] = *(const uint4*)(lds + rowb[n] + g*16);
        const unsigned char* vc = tabs + VAL_OFF + (size_t)u * VAL_KSTRIDE;
        #pragma unroll
        for (int m = 0; m < 4; m++) {
            uint4 a = *(const uint4*)(vc + (m*16 + r16)*VAL_CSTRIDE + g*16);
            #pragma unroll
            for (int n = 0; n < 4; n++) {
                f4 o = (f4){0.f,0.f,0.f,0.f};
                o = __builtin_amdgcn_mfma_f32_16x16x32_f16(bch8(a), bch8(b_pv[n]), o, 0, 0, 0);
                uint2 ov; ov.x = bcu(pkrtz(o[0], o[1])); ov.y = bcu(pkrtz(o[2], o[3]));
                if (mine[n])
                    *(uint2*)(lds + rowb[n] + m*32 + g*8) = ov;  // c = m*16+g*4..+3
            }
        }

        // tile t complete: publish (O rows of its 64 pixels are final)
        __threadfence_block();
        if (lane == 0)
            __hip_atomic_store(&flags[t], 1, __ATOMIC_RELEASE, __HIP_MEMORY_SCOPE_WORKGROUP);
    }

    // self-service store: wait only for MY tile, then store own row (coalesced)
    while (__hip_atomic_load(&flags[mytile], __ATOMIC_ACQUIRE,
                             __HIP_MEMORY_SCOPE_WORKGROUP) == 0) {
        __builtin_amdgcn_s_sleep(1);
    }
    {
        const uint4* r4 = (const uint4*)(lds + tid * ROW_STRIDE);
        float* op = obase + tid;
        #pragma unroll
        for (int q = 0; q < 8; q++) {
            uint4 v = r4[q];
            h2 x = bch2(v.x), y = bch2(v.y), z = bch2(v.z), w = bch2(v.w);
            op[(size_t)(8*q+0) * HW] = (float)x[0];
            op[(size_t)(8*q+1) * HW] = (float)x[1];
            op[(size_t)(8*q+2) * HW] = (float)y[0];
            op[(size_t)(8*q+3) * HW] = (float)y[1];
            op[(size_t)(8*q+4) * HW] = (float)z[0];
            op[(size_t)(8*q+5) * HW] = (float)z[1];
            op[(size_t)(8*q+6) * HW] = (float)w[0];
            op[(size_t)(8*q+7) * HW] = (float)w[1];
        }
    }
}

extern "C" void kernel_launch(void* const* d_in, const int* in_sizes, int n_in,
                              void* d_out, int out_size, void* d_ws, size_t ws_size,
                              hipStream_t stream) {
    const float* content = (const float*)d_in[0];
    const int*   seg     = (const int*)d_in[1];
    const float* key     = (const float*)d_in[2];
    const float* val     = (const float*)d_in[3];
    float* out = (float*)d_out;
    unsigned char* ws = (unsigned char*)d_ws;

    prep_kernel<<<7, 256, 0, stream>>>(key, val, ws);

    (void)hipFuncSetAttribute((const void*)main_kernel,
                              hipFuncAttributeMaxDynamicSharedMemorySize, LDS_TOTAL);
    main_kernel<<<NPIX/BLK, BLK, LDS_TOTAL, stream>>>(content, seg, ws, out);
}

// Round 13
// 40.851 us; speedup vs baseline: 1.9445x; 1.9445x over previous
//
#include <hip/hip_runtime.h>

typedef _Float16 h2 __attribute__((ext_vector_type(2)));
typedef _Float16 h8 __attribute__((ext_vector_type(8)));
typedef float f4 __attribute__((ext_vector_type(4)));
typedef unsigned int uint32;

#define NVAL 20
#define CDIM 64
#define HW   65536
#define NPIX (4*HW)

#define BLK   1024
#define NWAVE (BLK/64)            // 16
#define MAXTILES 35               // sum ceil(n_k/64) <= 16 + 19*(63/64) <= 34
#define MAXSLOT  (MAXTILES*64)    // 2240

// ---- packed f16 tables in ws (bytes) ----
#define KN_OFF      0
#define KN_KSTRIDE  2560          // per class: 20 j-rows x 128 B (c-contig, normalized)
#define VAL_OFF     (20*KN_KSTRIDE)      // 51200
#define VAL_KSTRIDE 4096          // per class: 64 c-rows x 64 B (32 j-slots)
#define VAL_CSTRIDE 64

// ---- LDS layout (bytes) ----
#define ROW_STRIDE 144            // 64 f16 (128 B) + 16 pad; 16B-aligned rows
#define ROWS_BYTES (BLK*ROW_STRIDE)          // 147456
#define INV_OFF   ROWS_BYTES                 // BLK f32 (4096)
#define PERM_OFF  (INV_OFF + BLK*4)          // MAXSLOT u16 (4480)
#define TCLS_OFF  (PERM_OFF + MAXSLOT*2)     // MAXTILES int (140->144)
#define FLAG_OFF  (TCLS_OFF + 144)           // MAXTILES int
#define CNT_OFF   (FLAG_OFF + 144)           // 24 int
#define LDS_TOTAL (CNT_OFF + 24*4 + 16)      // 156448 B (~152.8 KB) -> 1 block/CU

static __device__ __forceinline__ h2 bch2(uint32 u) { return __builtin_bit_cast(h2, u); }
static __device__ __forceinline__ uint32 bcu(h2 v) { return __builtin_bit_cast(uint32, v); }
static __device__ __forceinline__ h8 bch8(uint4 u) { return __builtin_bit_cast(h8, u); }
static __device__ __forceinline__ h2 pkrtz(float a, float b) {
    return __builtin_bit_cast(h2, __builtin_amdgcn_cvt_pkrtz(a, b));
}

// ---------------------------------------------------------------------------
// Prep: build packed f16 tables in ws (unchanged, verified since round 5).
// ---------------------------------------------------------------------------
__global__ void prep_kernel(const float* __restrict__ key,
                            const float* __restrict__ val,
                            unsigned char* __restrict__ ws) {
    int i = blockIdx.x * 256 + threadIdx.x;
    if (i < 20*CDIM) {
        int k = i >> 6, c = i & 63;
        const float* vb = val + k*NVAL*CDIM + c;     // val[k][j][c]
        float v[NVAL];
        float s = 0.f;
        #pragma unroll
        for (int j = 0; j < NVAL; j++) { v[j] = vb[j*CDIM]; s += v[j]; }
        float t = 0.f;
        for (int kk = 0; kk < 20; kk++) {
            const float* vb2 = val + kk*NVAL*CDIM + c;
            #pragma unroll
            for (int j = 0; j < NVAL; j++) t += vb2[j*CDIM];
        }
        float rest = (t - s) * (1.0f/NVAL);
        uint32* row = (uint32*)(ws + VAL_OFF + (size_t)k*VAL_KSTRIDE + c*VAL_CSTRIDE);
        #pragma unroll
        for (int jp = 0; jp < 10; jp++) row[jp] = bcu(pkrtz(v[2*jp], v[2*jp+1]));
        row[10] = bcu(pkrtz(rest, 0.f));
        #pragma unroll
        for (int jp = 11; jp < 16; jp++) row[jp] = 0u;
    } else if (i < 20*CDIM + 20*NVAL) {
        int idx = i - 20*CDIM;
        int k = idx / NVAL, j = idx % NVAL;
        const float* kb = key + k*CDIM*NVAL + j;     // key[k][c][j]
        float x[CDIM];
        float ssq = 0.f;
        #pragma unroll
        for (int c = 0; c < CDIM; c++) { x[c] = kb[c*NVAL]; ssq = fmaf(x[c], x[c], ssq); }
        float inv = 1.0f / fmaxf(sqrtf(ssq), 1e-12f);
        uint32* row = (uint32*)(ws + KN_OFF + (size_t)k*KN_KSTRIDE + j*128);
        #pragma unroll
        for (int cp = 0; cp < 32; cp++) row[cp] = bcu(pkrtz(x[2*cp]*inv, x[2*cp+1]*inv));
    }
}

// every thread redundantly scans the 20 counters: {my_base_slot, n_tiles}
static __device__ __forceinline__ int2 scan20(const int* cnt, int cls) {
    int acc = 0, mb = 0;
    #pragma unroll
    for (int k = 1; k <= 20; k++) {
        if (k == cls) mb = acc;
        acc += (cnt[k] + 63) & ~63;
    }
    return make_int2(mb, acc >> 6);
}

// ---------------------------------------------------------------------------
// Main: 256 blocks x 1024 threads (1 block/CU, 16 waves). Round-10 structure
// (class-pure 64-px wave-tiles, coalesced planar I/O via LDS rows, per-tile
// flags + self-service store, scan20, XCD swizzle). Delta: 1024-px window
// halves the class-padding inflation (max 2 tiles/wave instead of 3), which
// directly cuts the latency-bound middle phase; the flag self-store now
// overlaps the ~12 single-tile waves' stores with the 2-tile waves' compute.
// ---------------------------------------------------------------------------
__global__ __launch_bounds__(BLK, 4) void main_kernel(
        const float* __restrict__ content, const int* __restrict__ seg,
        const unsigned char* __restrict__ tabs, float* __restrict__ out) {
    extern __shared__ unsigned char lds[];
    float* invA = (float*)(lds + INV_OFF);
    unsigned short* perm = (unsigned short*)(lds + PERM_OFF);
    int* tcls  = (int*)(lds + TCLS_OFF);
    int* flags = (int*)(lds + FLAG_OFF);
    int* cnt   = (int*)(lds + CNT_OFF);

    const int tid  = threadIdx.x;
    const int bid  = (int)((blockIdx.x & 7) * 32 + (blockIdx.x >> 3));  // XCD swizzle (256 blocks)
    const int gp0  = bid * BLK;
    const int b    = gp0 >> 16;
    const int pim0 = gp0 & (HW - 1);
    float* obase = out + (size_t)b * CDIM * HW + pim0;

    if (tid < 24) cnt[tid] = 0;
    if (tid < MAXTILES) flags[tid] = 0;
    for (int i = tid; i < MAXSLOT; i += BLK) perm[i] = 0xFFFFu;
    __syncthreads();

    const int cls = seg[gp0 + tid] + 1;          // 1..19
    const int myrank = atomicAdd(&cnt[cls], 1);

    // stage content -> own LDS row (f16 pairs, unnormalized) + inv
    {
        const float* cptr = content + (size_t)b * CDIM * HW + pim0 + tid;
        uint2* myrow = (uint2*)(lds + tid * ROW_STRIDE);
        float ssq = 0.f;
        #pragma unroll
        for (int q = 0; q < 16; q++) {
            float f0 = cptr[(size_t)(4*q+0) * HW];
            float f1 = cptr[(size_t)(4*q+1) * HW];
            float f2 = cptr[(size_t)(4*q+2) * HW];
            float f3 = cptr[(size_t)(4*q+3) * HW];
            ssq = fmaf(f0,f0,ssq); ssq = fmaf(f1,f1,ssq);
            ssq = fmaf(f2,f2,ssq); ssq = fmaf(f3,f3,ssq);
            uint2 o; o.x = bcu(pkrtz(f0,f1)); o.y = bcu(pkrtz(f2,f3));
            myrow[q] = o;
        }
        invA[tid] = 1.0f / fmaxf(sqrtf(ssq), 1e-12f);
    }
    __syncthreads();                              // cnt + rows + inv complete

    const int2 s = scan20(cnt, cls);              // (my base slot, n tiles)
    const int myslot = s.x + myrank;
    const int mytile = myslot >> 6;
    {
        perm[myslot] = (unsigned short)tid;
        tcls[mytile] = cls;                       // class-pure tile
    }
    __syncthreads();                              // perm/tcls complete

    const int nt   = s.y;                         // ~20-23 typically (<= 34)
    const int wave = tid >> 6, lane = tid & 63;
    const int g = lane >> 4, r16 = lane & 15;

    for (int t = wave; t < nt; t += NWAVE) {
        const int u = __builtin_amdgcn_readfirstlane(tcls[t]);

        int rowb[4];
        float invn[4];
        bool mine[4];
        #pragma unroll
        for (int n = 0; n < 4; n++) {
            int v = perm[t*64 + n*16 + r16];
            mine[n] = (v != 0xFFFF);
            int l = mine[n] ? v : 0;
            rowb[n] = l * ROW_STRIDE;
            invn[n] = invA[l];
        }

        // ---- scores S^T[j][p] = sum_c Kn^T[j][c] * X^T[c][p] ----
        const unsigned char* knc = tabs + KN_OFF + (size_t)u * KN_KSTRIDE;
        uint4 a_sc[2][2];
        #pragma unroll
        for (int m = 0; m < 2; m++)
            #pragma unroll
            for (int ks = 0; ks < 2; ks++)
                a_sc[m][ks] = *(const uint4*)(knc + (m*16 + r16)*128 + (ks*32 + g*8)*2);
        uint4 b_sc[4][2];
        #pragma unroll
        for (int n = 0; n < 4; n++)
            #pragma unroll
            for (int ks = 0; ks < 2; ks++)
                b_sc[n][ks] = *(const uint4*)(lds + rowb[n] + (ks*32 + g*8)*2);

        f4 sacc[2][4];
        #pragma unroll
        for (int m = 0; m < 2; m++)
            #pragma unroll
            for (int n = 0; n < 4; n++) sacc[m][n] = (f4){0.f,0.f,0.f,0.f};
        #pragma unroll
        for (int ks = 0; ks < 2; ks++)
            #pragma unroll
            for (int m = 0; m < 2; m++)
                #pragma unroll
                for (int n = 0; n < 4; n++)
                    sacc[m][n] = __builtin_amdgcn_mfma_f32_16x16x32_f16(
                        bch8(a_sc[m][ks]), bch8(b_sc[n][ks]), sacc[m][n], 0, 0, 0);

        // ---- softmax; lane holds j = m*16 + g*4 + r for pixel p = n*16+r16 ----
        uint2 w0[4], w1[4];
        #pragma unroll
        for (int n = 0; n < 4; n++) {
            float e0[4], e1[4];
            #pragma unroll
            for (int r = 0; r < 4; r++) e0[r] = __expf(sacc[0][n][r] * invn[n]);
            float arg1 = (g == 0) ? invn[n] : 0.0f;     // j>=20 masked
            #pragma unroll
            for (int r = 0; r < 4; r++) e1[r] = __expf(sacc[1][n][r] * arg1);
            float sum = e0[0]+e0[1]+e0[2]+e0[3];
            sum += (g == 0) ? (e1[0]+e1[1]+e1[2]+e1[3]) : 0.0f;
            sum += __shfl_xor(sum, 16, 64);
            sum += __shfl_xor(sum, 32, 64);
            float wsc = 1.0f / sum;
            w0[n].x = bcu(pkrtz(e0[0]*wsc, e0[1]*wsc));
            w0[n].y = bcu(pkrtz(e0[2]*wsc, e0[3]*wsc));
            uint2 t1;
            if (g == 0)      { t1.x = bcu(pkrtz(e1[0]*wsc, e1[1]*wsc));
                               t1.y = bcu(pkrtz(e1[2]*wsc, e1[3]*wsc)); }
            else if (g == 1) { t1.x = 0x00003C00u; t1.y = 0u; }  // j20=1.0 (rest)
            else             { t1.x = 0u; t1.y = 0u; }
            w1[n] = t1;
        }
        // write W over own row (X is dead): j-contiguous 32 f16 at offset 0
        #pragma unroll
        for (int n = 0; n < 4; n++) {
            if (mine[n]) {
                *(uint2*)(lds + rowb[n] + g*8)      = w0[n];
                *(uint2*)(lds + rowb[n] + 32 + g*8) = w1[n];
            }
        }

        // ---- PV O^T[c][p] = sum_j V^T[c][j] * W^T[j][p] (K=32) ----
        uint4 b_pv[4];
        #pragma unroll
        for (int n = 0; n < 4; n++)
            b_pv[n] = *(const uint4*)(lds + rowb[n] + g*16);
        const unsigned char* vc = tabs + VAL_OFF + (size_t)u * VAL_KSTRIDE;
        #pragma unroll
        for (int m = 0; m < 4; m++) {
            uint4 a = *(const uint4*)(vc + (m*16 + r16)*VAL_CSTRIDE + g*16);
            #pragma unroll
            for (int n = 0; n < 4; n++) {
                f4 o = (f4){0.f,0.f,0.f,0.f};
                o = __builtin_amdgcn_mfma_f32_16x16x32_f16(bch8(a), bch8(b_pv[n]), o, 0, 0, 0);
                uint2 ov; ov.x = bcu(pkrtz(o[0], o[1])); ov.y = bcu(pkrtz(o[2], o[3]));
                if (mine[n])
                    *(uint2*)(lds + rowb[n] + m*32 + g*8) = ov;  // c = m*16+g*4..+3
            }
        }

        // tile t complete: publish (O rows of its 64 pixels are final)
        __threadfence_block();
        if (lane == 0)
            __hip_atomic_store(&flags[t], 1, __ATOMIC_RELEASE, __HIP_MEMORY_SCOPE_WORKGROUP);
    }

    // self-service store: wait only for MY tile, then store own row (coalesced)
    while (__hip_atomic_load(&flags[mytile], __ATOMIC_ACQUIRE,
                             __HIP_MEMORY_SCOPE_WORKGROUP) == 0) {
        __builtin_amdgcn_s_sleep(1);
    }
    {
        const uint4* r4 = (const uint4*)(lds + tid * ROW_STRIDE);
        float* op = obase + tid;
        #pragma unroll
        for (int q = 0; q < 8; q++) {
            uint4 v = r4[q];
            h2 x = bch2(v.x), y = bch2(v.y), z = bch2(v.z), w = bch2(v.w);
            op[(size_t)(8*q+0) * HW] = (float)x[0];
            op[(size_t)(8*q+1) * HW] = (float)x[1];
            op[(size_t)(8*q+2) * HW] = (float)y[0];
            op[(size_t)(8*q+3) * HW] = (float)y[1];
            op[(size_t)(8*q+4) * HW] = (float)z[0];
            op[(size_t)(8*q+5) * HW] = (float)z[1];
            op[(size_t)(8*q+6) * HW] = (float)w[0];
            op[(size_t)(8*q+7) * HW] = (float)w[1];
        }
    }
}

extern "C" void kernel_launch(void* const* d_in, const int* in_sizes, int n_in,
                              void* d_out, int out_size, void* d_ws, size_t ws_size,
                              hipStream_t stream) {
    const float* content = (const float*)d_in[0];
    const int*   seg     = (const int*)d_in[1];
    const float* key     = (const float*)d_in[2];
    const float* val     = (const float*)d_in[3];
    float* out = (float*)d_out;
    unsigned char* ws = (unsigned char*)d_ws;

    prep_kernel<<<7, 256, 0, stream>>>(key, val, ws);

    (void)hipFuncSetAttribute((const void*)main_kernel,
                              hipFuncAttributeMaxDynamicSharedMemorySize, LDS_TOTAL);
    main_kernel<<<NPIX/BLK, BLK, LDS_TOTAL, stream>>>(content, seg, ws, out);
}